// Round 16
// baseline (40.516 us; speedup 1.0000x reference)
//
#include <hip/hip_runtime.h>
#include <cmath>

// B=1, H=64, W=128, C=256, 8 heads x 32 dim, 7x7 window.
// R16 = R15 with (1) qkv BN=192 (A re-reads 6->4, 48->32MB; 512 blocks
// = 2.0/CU), (2) proj BN=64 (256 -> 512 blocks = 2.0/CU; was 1.0/CU with
// zero drain overlap). prep_w + na verbatim. Bit-identical math (checksum:
// absmax must stay exactly 4.882812e-4).
#define HH 64
#define WW 128
#define CC 256
#define NHEAD 8
#define HDIM 32
#define NPIX (HH*WW)       // 8192
#define QKV_N (3*CC)       // 768

typedef __attribute__((ext_vector_type(8))) short short8v;  // 8 bf16
typedef __attribute__((ext_vector_type(4))) short short4v;  // 4 bf16
typedef __attribute__((ext_vector_type(4))) float f32x4;
typedef unsigned int u32;

__device__ __forceinline__ short f2bf(float f) {
    unsigned int u = __builtin_bit_cast(unsigned int, f);
    u += 0x7fffu + ((u >> 16) & 1u);
    return (short)(u >> 16);
}

// ---------------------------------------------------------------------------
// prep_w: weight transposes only (R15 verbatim).
// ---------------------------------------------------------------------------
__global__ __launch_bounds__(256)
void prep_w(const float* __restrict__ w_qkv, const float* __restrict__ w_proj,
            short* __restrict__ wq_t, short* __restrict__ wp_t)
{
    __shared__ float tile[32][33];
    int idx = blockIdx.x;
    const float* src; short* dst; int N;
    if (idx < 192) { src = w_qkv;  dst = wq_t; N = QKV_N; }
    else { idx -= 192; src = w_proj; dst = wp_t; N = CC; }
    const int nbx = N / 32;
    const int bn = (idx % nbx) * 32;
    const int bk = (idx / nbx) * 32;
    const int tx = threadIdx.x & 31, ty = threadIdx.x >> 5;
#pragma unroll
    for (int i = 0; i < 32; i += 8)
        tile[ty + i][tx] = src[(size_t)(bk + ty + i) * N + bn + tx];
    __syncthreads();
#pragma unroll
    for (int i = 0; i < 32; i += 8)
        dst[(size_t)(bn + ty + i) * CC + bk + tx] = f2bf(tile[tx][ty + i]);
}

// ---------------------------------------------------------------------------
// QKV GEMM: qkv_bf = x(fp32) * wq_t^T + b_qkv. BM=64 BN=192 BK=32, grid
// (128,4)=512 blocks (2.0/CU), 4 waves 2x2 (WM=32, WN=96).
// A: fp32 reg-staged -> f2bf -> LDS padded rows (R15-proven).
// B: gload_lds double-buffered, linear, 3 granules/thread.
// ---------------------------------------------------------------------------
#define LDA 40

__global__ __launch_bounds__(256)
void gemm_qkv(const float* __restrict__ x, const short* __restrict__ Bt,
              const float* __restrict__ bias, short* __restrict__ Cbf)
{
    __shared__ short As[2][64 * LDA];    // 10240 B
    __shared__ short Bs[2][192 * 32];    // 24576 B

    const int tid = threadIdx.x, lane = tid & 63, wave = tid >> 6;
    const int bm = blockIdx.x * 64, bn = blockIdx.y * 192;
    const int wm0 = (wave >> 1) * 32, wn0 = (wave & 1) * 96;
    const int l15 = lane & 15, l4 = lane >> 4;
    const int arow = tid >> 2, ako = (tid & 3) * 8;

    float4 a0, a1;
    auto loadA = [&](int t) {
        const float* p = x + (size_t)(bm + arow) * CC + t * 32 + ako;
        a0 = *(const float4*)p; a1 = *(const float4*)(p + 4);
    };
    auto writeA = [&](int buf) {
        short8v v;
        v[0] = f2bf(a0.x); v[1] = f2bf(a0.y); v[2] = f2bf(a0.z); v[3] = f2bf(a0.w);
        v[4] = f2bf(a1.x); v[5] = f2bf(a1.y); v[6] = f2bf(a1.z); v[7] = f2bf(a1.w);
        *(short8v*)&As[buf][arow * LDA + ako] = v;
    };
    auto stageB = [&](int buf, int t) {
#pragma unroll
        for (int i = 0; i < 3; ++i) {
            const int g = tid + 256 * i;
            __builtin_amdgcn_global_load_lds(
                (const __attribute__((address_space(1))) u32*)
                    (Bt + (size_t)(bn + (g >> 2)) * CC + t * 32 + (g & 3) * 8),
                (__attribute__((address_space(3))) u32*)&Bs[buf][g * 8], 16, 0, 0);
        }
    };

    f32x4 acc[2][6];
#pragma unroll
    for (int i = 0; i < 2; ++i)
#pragma unroll
        for (int j = 0; j < 6; ++j) acc[i][j] = (f32x4){0.f, 0.f, 0.f, 0.f};

    loadA(0);
    writeA(0);
    stageB(0, 0);
    loadA(1);

    for (int t = 0; t < 8; ++t) {
        const int cur = t & 1;
        __syncthreads();                 // buf[cur]: B landed, A writes visible
        if (t + 1 < 8) {
            writeA(cur ^ 1);             // buf^1 reads finished in iter t-1
            stageB(cur ^ 1, t + 1);
            if (t + 2 < 8) loadA(t + 2);
        }

        short8v af[2], bf[6];
#pragma unroll
        for (int fm = 0; fm < 2; ++fm)
            af[fm] = *(const short8v*)&As[cur][(wm0 + fm * 16 + l15) * LDA + l4 * 8];
#pragma unroll
        for (int fn = 0; fn < 6; ++fn)
            bf[fn] = *(const short8v*)&Bs[cur][(wn0 + fn * 16 + l15) * 32 + l4 * 8];
#pragma unroll
        for (int fm = 0; fm < 2; ++fm)
#pragma unroll
            for (int fn = 0; fn < 6; ++fn)
                acc[fm][fn] = __builtin_amdgcn_mfma_f32_16x16x32_bf16(
                    af[fm], bf[fn], acc[fm][fn], 0, 0, 0);
    }

    const int col0 = bn + wn0 + l15;
    const int row0 = bm + wm0 + l4 * 4;
#pragma unroll
    for (int fn = 0; fn < 6; ++fn) {
        const float bv = bias[col0 + fn * 16];
#pragma unroll
        for (int fm = 0; fm < 2; ++fm)
#pragma unroll
            for (int r = 0; r < 4; ++r)
                Cbf[(size_t)(row0 + fm * 16 + r) * QKV_N + col0 + fn * 16] =
                    f2bf(acc[fm][fn][r] + bv);
    }
}

// ---------------------------------------------------------------------------
// proj GEMM: BM=64 BN=64, grid (128,4)=512 blocks (2.0/CU; was 1.0/CU).
// Both operands gload_lds double-buffered, linear (R6-proven path).
// ---------------------------------------------------------------------------
__global__ __launch_bounds__(256)
void gemm_proj(const short* __restrict__ A, const short* __restrict__ Bt,
               const float* __restrict__ bias, float* __restrict__ C)
{
    constexpr int BM = 64, BN = 64, BK = 32;
    __shared__ short As[2][BM * BK];     // 8192 B
    __shared__ short Bs[2][BN * BK];     // 8192 B

    const int tid = threadIdx.x, lane = tid & 63, wave = tid >> 6;
    const int wm0 = (wave >> 1) * 32, wn0 = (wave & 1) * 32;
    const int bm = blockIdx.x * BM, bn = blockIdx.y * BN;
    const int l15 = lane & 15, l4 = lane >> 4;

    f32x4 acc[2][2];
#pragma unroll
    for (int i = 0; i < 2; ++i)
#pragma unroll
        for (int j = 0; j < 2; ++j) acc[i][j] = (f32x4){0.f, 0.f, 0.f, 0.f};

    auto stage = [&](int buf, int t) {
        __builtin_amdgcn_global_load_lds(
            (const __attribute__((address_space(1))) u32*)
                (A + (size_t)(bm + (tid >> 2)) * CC + t * BK + (tid & 3) * 8),
            (__attribute__((address_space(3))) u32*)&As[buf][tid * 8], 16, 0, 0);
        __builtin_amdgcn_global_load_lds(
            (const __attribute__((address_space(1))) u32*)
                (Bt + (size_t)(bn + (tid >> 2)) * CC + t * BK + (tid & 3) * 8),
            (__attribute__((address_space(3))) u32*)&Bs[buf][tid * 8], 16, 0, 0);
    };

    stage(0, 0);

    for (int t = 0; t < 8; ++t) {
        const int cur = t & 1;
        __syncthreads();
        if (t + 1 < 8) stage(cur ^ 1, t + 1);

        short8v af[2], bf[2];
#pragma unroll
        for (int fm = 0; fm < 2; ++fm)
            af[fm] = *(const short8v*)&As[cur][(wm0 + fm * 16 + l15) * BK + l4 * 8];
#pragma unroll
        for (int fn = 0; fn < 2; ++fn)
            bf[fn] = *(const short8v*)&Bs[cur][(wn0 + fn * 16 + l15) * BK + l4 * 8];
#pragma unroll
        for (int fm = 0; fm < 2; ++fm)
#pragma unroll
            for (int fn = 0; fn < 2; ++fn)
                acc[fm][fn] = __builtin_amdgcn_mfma_f32_16x16x32_bf16(
                    af[fm], bf[fn], acc[fm][fn], 0, 0, 0);
    }

    const int col0 = bn + wn0 + l15;
    const int row0 = bm + wm0 + l4 * 4;
#pragma unroll
    for (int fn = 0; fn < 2; ++fn) {
        const float bv = bias[col0 + fn * 16];
#pragma unroll
        for (int fm = 0; fm < 2; ++fm)
#pragma unroll
            for (int r = 0; r < 4; ++r)
                C[(size_t)(row0 + fm * 16 + r) * CC + col0 + fn * 16] =
                    acc[fm][fn][r] + bv;
    }
}

// ---------------------------------------------------------------------------
// Neighborhood attention (R15 verbatim): 16x8-px blocks, 8 waves,
// halo-shared 14x22 union. LDS 52.6KB -> 3 blocks/CU.
// ---------------------------------------------------------------------------
#define LDK    40
#define KSLOT2 344
#define VSLOT2 392

__global__ __launch_bounds__(512)
void na_mfma(const short* __restrict__ qkv, short* __restrict__ attn)
{
    __shared__ short Ksh[KSLOT2 * LDK];   // 27520 B
    __shared__ short Vsh[32 * VSLOT2];    // 25088 B  [d][slot]

    const int x0 = blockIdx.x * 16;
    const int y0 = blockIdx.y * 8;
    const int head = blockIdx.z;
    const int tid = threadIdx.x, lane = tid & 63, w = tid >> 6;
    const int rs  = min(max(y0 - 3, 0), HH - 7);
    const int wsx = x0 - 3;

    for (int idx = tid; idx < 1232; idx += 512) {
        int g = idx & 3, rc = idx >> 2;
        int i = rc / 22, c = rc - i * 22;
        int yy = rs + i, xx = wsx + c;
        if (yy < HH && (unsigned)xx < WW) {
            *(short8v*)&Ksh[(i * 24 + c) * LDK + g * 8] =
                *(const short8v*)(qkv + (size_t)(yy * WW + xx) * QKV_N
                                  + CC + head * HDIM + g * 8);
        }
    }
    for (int idx = tid; idx < 392; idx += 512) {
        int g = idx & 3, q2 = idx >> 2;
        int i = q2 / 6, cq = q2 - i * 6;
        int yy = rs + i;
        short8v vv[4];
#pragma unroll
        for (int j = 0; j < 4; ++j) {
            int c = cq * 4 + j, xx = wsx + c;
            if (i < 14 && yy < HH && c < 22 && (unsigned)xx < WW)
                vv[j] = *(const short8v*)(qkv + (size_t)(yy * WW + xx) * QKV_N
                                          + 2 * CC + head * HDIM + g * 8);
            else {
                short8v z = {0,0,0,0,0,0,0,0};
                vv[j] = z;
            }
        }
#pragma unroll
        for (int jd = 0; jd < 8; ++jd) {
            short4v s4 = {vv[0][jd], vv[1][jd], vv[2][jd], vv[3][jd]};
            *(short4v*)&Vsh[(g * 8 + jd) * VSLOT2 + q2 * 4] = s4;
        }
    }

    const int l15 = lane & 15, l4 = lane >> 4;
    const int y = y0 + w;
    short8v qf = *(const short8v*)(qkv + (size_t)(y * WW + x0 + l15) * QKV_N
                                   + head * HDIM + l4 * 8);
    __syncthreads();

    const int wbase = (min(max(y - 3, 0), HH - 7) - rs) * 24;

    f32x4 sacc[11];
#pragma unroll
    for (int kc = 0; kc < 11; ++kc) {
        short8v kf = *(const short8v*)&Ksh[(wbase + kc * 16 + l15) * LDK + l4 * 8];
        f32x4 z = {0.f, 0.f, 0.f, 0.f};
        sacc[kc] = __builtin_amdgcn_mfma_f32_16x16x32_bf16(kf, qf, z, 0, 0, 0);
    }

    const int xq = x0 + l15;
    const int cw = min(max(xq - 3, 0), WW - 7) - wsx;
    const float scale = 0.17677669529663687f;
    float lsum = 0.f;
#pragma unroll
    for (int kc = 0; kc < 11; ++kc) {
#pragma unroll
        for (int r = 0; r < 4; ++r) {
            int kl = kc * 16 + l4 * 4 + r;
            int row = kl / 24;
            int c = kl - row * 24;
            bool valid = (row < 7) && (c >= cw) && (c <= cw + 6);
            float e = valid ? __expf(sacc[kc][r] * scale) : 0.f;
            sacc[kc][r] = e;
            lsum += e;
        }
    }
    lsum += __shfl_xor(lsum, 16);
    lsum += __shfl_xor(lsum, 32);
    const float inv = 1.0f / lsum;

    short4v pf[12];
#pragma unroll
    for (int kc = 0; kc < 11; ++kc) {
        short4v pk;
#pragma unroll
        for (int r = 0; r < 4; ++r) pk[r] = f2bf(sacc[kc][r] * inv);
        pf[kc] = pk;
    }
    pf[11] = (short4v){0, 0, 0, 0};

    const int src0 = ((l4 & 1) << 5) + l15;
    const int src1 = src0 + 16;
    const bool hi = (l4 & 2) != 0;
    f32x4 oacc[2];
    oacc[0] = (f32x4){0.f, 0.f, 0.f, 0.f};
    oacc[1] = (f32x4){0.f, 0.f, 0.f, 0.f};
#pragma unroll
    for (int kc2 = 0; kc2 < 6; ++kc2) {
        int lo0 = ((const int*)&pf[2 * kc2])[0];
        int lo1 = ((const int*)&pf[2 * kc2])[1];
        int hi0 = ((const int*)&pf[2 * kc2 + 1])[0];
        int hi1 = ((const int*)&pf[2 * kc2 + 1])[1];
        int a0 = __shfl(lo0, src0), a1 = __shfl(lo1, src0);
        int a2 = __shfl(lo0, src1), a3 = __shfl(lo1, src1);
        int b0 = __shfl(hi0, src0), b1 = __shfl(hi1, src0);
        int b2 = __shfl(hi0, src1), b3 = __shfl(hi1, src1);
        int w0 = hi ? b0 : a0, w1 = hi ? b1 : a1;
        int w2 = hi ? b2 : a2, w3 = hi ? b3 : a3;
        int wv[4] = {w0, w1, w2, w3};
        short8v bfrag = *(const short8v*)wv;
#pragma unroll
        for (int nc = 0; nc < 2; ++nc) {
            short8v vf = *(const short8v*)&Vsh[(nc * 16 + l15) * VSLOT2
                                               + wbase + kc2 * 32 + l4 * 8];
            oacc[nc] = __builtin_amdgcn_mfma_f32_16x16x32_bf16(vf, bfrag, oacc[nc], 0, 0, 0);
        }
    }

    short* op = attn + (size_t)(y * WW + x0 + l15) * CC + head * HDIM;
#pragma unroll
    for (int nc = 0; nc < 2; ++nc) {
        short4v o;
#pragma unroll
        for (int r = 0; r < 4; ++r) o[r] = f2bf(oacc[nc][r]);
        *(short4v*)(op + nc * 16 + l4 * 4) = o;
    }
}

// ---------------------------------------------------------------------------
extern "C" void kernel_launch(void* const* d_in, const int* in_sizes, int n_in,
                              void* d_out, int out_size, void* d_ws, size_t ws_size,
                              hipStream_t stream)
{
    const float* x      = (const float*)d_in[0];
    const float* w_qkv  = (const float*)d_in[1];
    const float* b_qkv  = (const float*)d_in[2];
    const float* w_proj = (const float*)d_in[3];
    const float* b_proj = (const float*)d_in[4];
    float* out = (float*)d_out;

    char* ws = (char*)d_ws;
    short* qkv_bf  = (short*)ws;                    // 8192x768 bf16 = 12 MB
    short* attn_bf = (short*)(ws + 12582912);       // 8192x256 bf16 =  4 MB
    short* wq_t    = (short*)(ws + 16777216);       // 768x256 bf16
    short* wp_t    = (short*)(ws + 17170432);       // 256x256 bf16

    prep_w<<<dim3(256), dim3(256), 0, stream>>>(w_qkv, w_proj, wq_t, wp_t);

    // QKV: BN=192, grid (128,4) = 512 blocks = 2.0/CU; A re-reads 6->4
    gemm_qkv<<<dim3(NPIX / 64, QKV_N / 192), dim3(256), 0, stream>>>(
        x, wq_t, b_qkv, qkv_bf);

    // attention: 16x8-px blocks, 8 waves, grid (8,8,8) = 512 blocks
    na_mfma<<<dim3(WW / 16, HH / 8, NHEAD), dim3(512), 0, stream>>>(qkv_bf, attn_bf);

    // proj: BN=64, grid (128,4) = 512 blocks = 2.0/CU (was 1.0/CU)
    gemm_proj<<<dim3(NPIX / 64, CC / 64), dim3(256), 0, stream>>>(
        attn_bf, wp_t, b_proj, out);
}

// Round 18
// 39.432 us; speedup vs baseline: 1.0275x; 1.0275x over previous
//
#include <hip/hip_runtime.h>
#include <cmath>

// B=1, H=64, W=128, C=256, 8 heads x 32 dim, 7x7 window.
// R18 = R14 VERBATIM (best measured: 39.65us). Restore after R17's
// cooperative-launch experiment failed to execute under graph capture.
// Checksum: absmax must stay exactly 4.882812e-4.
#define HH 64
#define WW 128
#define CC 256
#define NHEAD 8
#define HDIM 32
#define NPIX (HH*WW)       // 8192
#define QKV_N (3*CC)       // 768

typedef __attribute__((ext_vector_type(8))) short short8v;  // 8 bf16
typedef __attribute__((ext_vector_type(4))) short short4v;  // 4 bf16
typedef __attribute__((ext_vector_type(4))) float f32x4;
typedef unsigned int u32;

__device__ __forceinline__ short f2bf(float f) {
    unsigned int u = __builtin_bit_cast(unsigned int, f);
    u += 0x7fffu + ((u >> 16) & 1u);
    return (short)(u >> 16);
}

// ---------------------------------------------------------------------------
// prep: x->bf16 (1024 blks) + weight transposes (256 blks).
// ---------------------------------------------------------------------------
__global__ __launch_bounds__(256)
void prep(const float* __restrict__ x, const float* __restrict__ w_qkv,
          const float* __restrict__ w_proj, short* __restrict__ x_bf,
          short* __restrict__ wqkv_t, short* __restrict__ wproj_t)
{
    __shared__ float tile[32][33];
    const int b = blockIdx.x;
    if (b < 1024) {
        const int i = b * 256 + threadIdx.x;
        float4 a = ((const float4*)x)[i * 2];
        float4 c = ((const float4*)x)[i * 2 + 1];
        short8v o;
        o[0] = f2bf(a.x); o[1] = f2bf(a.y); o[2] = f2bf(a.z); o[3] = f2bf(a.w);
        o[4] = f2bf(c.x); o[5] = f2bf(c.y); o[6] = f2bf(c.z); o[7] = f2bf(c.w);
        ((short8v*)x_bf)[i] = o;
        return;
    }
    const float* src; short* dst; int N, idx;
    if (b < 1216) { idx = b - 1024; src = w_qkv;  dst = wqkv_t;  N = QKV_N; }
    else          { idx = b - 1216; src = w_proj; dst = wproj_t; N = CC;    }
    const int nbx = N / 32;
    const int bn = (idx % nbx) * 32;
    const int bk = (idx / nbx) * 32;
    const int tx = threadIdx.x & 31, ty = threadIdx.x >> 5;
#pragma unroll
    for (int i = 0; i < 32; i += 8)
        tile[ty + i][tx] = src[(size_t)(bk + ty + i) * N + bn + tx];
    __syncthreads();
#pragma unroll
    for (int i = 0; i < 32; i += 8)
        dst[(size_t)(bn + ty + i) * CC + bk + tx] = f2bf(tile[tx][ty + i]);
}

// ---------------------------------------------------------------------------
// bf16 MFMA GEMM: gload_lds double-buffered staging (R6-proven).
// ---------------------------------------------------------------------------
template<int BM, int BN, bool OUT32>
__global__ __launch_bounds__(256)
void gemm_bf(const short* __restrict__ A, const short* __restrict__ Bt,
             const float* __restrict__ bias, void* __restrict__ Cv,
             int M, int N, int K)
{
    constexpr int BK  = 32;
    constexpr int NGA = BM * BK / 2048;
    constexpr int NGB = BN * BK / 2048;
    __shared__ short As[2][BM * BK];
    __shared__ short Bs[2][BN * BK];

    const int tid  = threadIdx.x;
    const int lane = tid & 63;
    const int wave = tid >> 6;
    constexpr int WM = BM / 2, WN = BN / 2;
    constexpr int FM = WM / 16, FN = WN / 16;
    const int wm0 = (wave >> 1) * WM;
    const int wn0 = (wave & 1) * WN;
    const int bm = blockIdx.x * BM, bn = blockIdx.y * BN;
    const int l15 = lane & 15, l4 = lane >> 4;

    f32x4 acc[FM][FN];
#pragma unroll
    for (int i = 0; i < FM; ++i)
#pragma unroll
        for (int j = 0; j < FN; ++j) acc[i][j] = (f32x4){0.f, 0.f, 0.f, 0.f};

    auto stage = [&](int buf, int t) {
#pragma unroll
        for (int i = 0; i < NGA; ++i) {
            const int g = tid + 256 * i;
            __builtin_amdgcn_global_load_lds(
                (const __attribute__((address_space(1))) u32*)
                    (A + (size_t)(bm + (g >> 2)) * K + t * BK + (g & 3) * 8),
                (__attribute__((address_space(3))) u32*)&As[buf][g * 8],
                16, 0, 0);
        }
#pragma unroll
        for (int i = 0; i < NGB; ++i) {
            const int g = tid + 256 * i;
            __builtin_amdgcn_global_load_lds(
                (const __attribute__((address_space(1))) u32*)
                    (Bt + (size_t)(bn + (g >> 2)) * K + t * BK + (g & 3) * 8),
                (__attribute__((address_space(3))) u32*)&Bs[buf][g * 8],
                16, 0, 0);
        }
    };

    stage(0, 0);
    const int NT = K / BK;

    for (int t = 0; t < NT; ++t) {
        const int cur = t & 1;
        __syncthreads();
        if (t + 1 < NT) stage(cur ^ 1, t + 1);

        short8v af[FM], bf[FN];
#pragma unroll
        for (int fm = 0; fm < FM; ++fm)
            af[fm] = *(const short8v*)&As[cur][(wm0 + fm * 16 + l15) * BK + l4 * 8];
#pragma unroll
        for (int fn = 0; fn < FN; ++fn)
            bf[fn] = *(const short8v*)&Bs[cur][(wn0 + fn * 16 + l15) * BK + l4 * 8];
#pragma unroll
        for (int fm = 0; fm < FM; ++fm)
#pragma unroll
            for (int fn = 0; fn < FN; ++fn)
                acc[fm][fn] = __builtin_amdgcn_mfma_f32_16x16x32_bf16(
                    af[fm], bf[fn], acc[fm][fn], 0, 0, 0);
    }

    const int col0 = bn + wn0 + l15;
    const int row0 = bm + wm0 + l4 * 4;
#pragma unroll
    for (int fn = 0; fn < FN; ++fn) {
        const float bv = bias[col0 + fn * 16];
#pragma unroll
        for (int fm = 0; fm < FM; ++fm)
#pragma unroll
            for (int r = 0; r < 4; ++r) {
                const size_t off = (size_t)(row0 + fm * 16 + r) * N + col0 + fn * 16;
                if (OUT32) ((float*)Cv)[off] = acc[fm][fn][r] + bv;
                else       ((short*)Cv)[off] = f2bf(acc[fm][fn][r] + bv);
            }
    }
}

// ---------------------------------------------------------------------------
// Neighborhood attention, halo-shared: 16x8-px blocks, 8 waves (512 thr),
// wave w owns row y0+w. Union = 14x22, slot = i*24+c. Per-wave math = R6.
// LDS 52.6KB -> 3 blocks/CU.
// ---------------------------------------------------------------------------
#define LDK    40
#define KSLOT2 344   // max S-read slot = 168 + 175 = 343
#define VSLOT2 392   // max PV-read slot = 168 + 216 + 7 = 391

__global__ __launch_bounds__(512)
void na_mfma(const short* __restrict__ qkv, short* __restrict__ attn)
{
    __shared__ short Ksh[KSLOT2 * LDK];   // 27520 B
    __shared__ short Vsh[32 * VSLOT2];    // 25088 B  [d][slot]

    const int x0 = blockIdx.x * 16;
    const int y0 = blockIdx.y * 8;
    const int head = blockIdx.z;
    const int tid = threadIdx.x, lane = tid & 63, w = tid >> 6;
    const int rs  = min(max(y0 - 3, 0), HH - 7);
    const int wsx = x0 - 3;

    for (int idx = tid; idx < 1232; idx += 512) {
        int g = idx & 3, rc = idx >> 2;
        int i = rc / 22, c = rc - i * 22;
        int yy = rs + i, xx = wsx + c;
        if (yy < HH && (unsigned)xx < WW) {
            *(short8v*)&Ksh[(i * 24 + c) * LDK + g * 8] =
                *(const short8v*)(qkv + (size_t)(yy * WW + xx) * QKV_N
                                  + CC + head * HDIM + g * 8);
        }
    }
    for (int idx = tid; idx < 392; idx += 512) {
        int g = idx & 3, q2 = idx >> 2;
        int i = q2 / 6, cq = q2 - i * 6;
        int yy = rs + i;
        short8v vv[4];
#pragma unroll
        for (int j = 0; j < 4; ++j) {
            int c = cq * 4 + j, xx = wsx + c;
            if (i < 14 && yy < HH && c < 22 && (unsigned)xx < WW)
                vv[j] = *(const short8v*)(qkv + (size_t)(yy * WW + xx) * QKV_N
                                          + 2 * CC + head * HDIM + g * 8);
            else {
                short8v z = {0,0,0,0,0,0,0,0};
                vv[j] = z;
            }
        }
#pragma unroll
        for (int jd = 0; jd < 8; ++jd) {
            short4v s4 = {vv[0][jd], vv[1][jd], vv[2][jd], vv[3][jd]};
            *(short4v*)&Vsh[(g * 8 + jd) * VSLOT2 + q2 * 4] = s4;
        }
    }

    const int l15 = lane & 15, l4 = lane >> 4;
    const int y = y0 + w;
    short8v qf = *(const short8v*)(qkv + (size_t)(y * WW + x0 + l15) * QKV_N
                                   + head * HDIM + l4 * 8);
    __syncthreads();

    const int wbase = (min(max(y - 3, 0), HH - 7) - rs) * 24;

    f32x4 sacc[11];
#pragma unroll
    for (int kc = 0; kc < 11; ++kc) {
        short8v kf = *(const short8v*)&Ksh[(wbase + kc * 16 + l15) * LDK + l4 * 8];
        f32x4 z = {0.f, 0.f, 0.f, 0.f};
        sacc[kc] = __builtin_amdgcn_mfma_f32_16x16x32_bf16(kf, qf, z, 0, 0, 0);
    }

    const int xq = x0 + l15;
    const int cw = min(max(xq - 3, 0), WW - 7) - wsx;
    const float scale = 0.17677669529663687f;
    float lsum = 0.f;
#pragma unroll
    for (int kc = 0; kc < 11; ++kc) {
#pragma unroll
        for (int r = 0; r < 4; ++r) {
            int kl = kc * 16 + l4 * 4 + r;
            int row = kl / 24;
            int c = kl - row * 24;
            bool valid = (row < 7) && (c >= cw) && (c <= cw + 6);
            float e = valid ? __expf(sacc[kc][r] * scale) : 0.f;
            sacc[kc][r] = e;
            lsum += e;
        }
    }
    lsum += __shfl_xor(lsum, 16);
    lsum += __shfl_xor(lsum, 32);
    const float inv = 1.0f / lsum;

    short4v pf[12];
#pragma unroll
    for (int kc = 0; kc < 11; ++kc) {
        short4v pk;
#pragma unroll
        for (int r = 0; r < 4; ++r) pk[r] = f2bf(sacc[kc][r] * inv);
        pf[kc] = pk;
    }
    pf[11] = (short4v){0, 0, 0, 0};

    const int src0 = ((l4 & 1) << 5) + l15;
    const int src1 = src0 + 16;
    const bool hi = (l4 & 2) != 0;
    f32x4 oacc[2];
    oacc[0] = (f32x4){0.f, 0.f, 0.f, 0.f};
    oacc[1] = (f32x4){0.f, 0.f, 0.f, 0.f};
#pragma unroll
    for (int kc2 = 0; kc2 < 6; ++kc2) {
        int lo0 = ((const int*)&pf[2 * kc2])[0];
        int lo1 = ((const int*)&pf[2 * kc2])[1];
        int hi0 = ((const int*)&pf[2 * kc2 + 1])[0];
        int hi1 = ((const int*)&pf[2 * kc2 + 1])[1];
        int a0 = __shfl(lo0, src0), a1 = __shfl(lo1, src0);
        int a2 = __shfl(lo0, src1), a3 = __shfl(lo1, src1);
        int b0 = __shfl(hi0, src0), b1 = __shfl(hi1, src0);
        int b2 = __shfl(hi0, src1), b3 = __shfl(hi1, src1);
        int w0 = hi ? b0 : a0, w1 = hi ? b1 : a1;
        int w2 = hi ? b2 : a2, w3 = hi ? b3 : a3;
        int wv[4] = {w0, w1, w2, w3};
        short8v bfrag = *(const short8v*)wv;
#pragma unroll
        for (int nc = 0; nc < 2; ++nc) {
            short8v vf = *(const short8v*)&Vsh[(nc * 16 + l15) * VSLOT2
                                               + wbase + kc2 * 32 + l4 * 8];
            oacc[nc] = __builtin_amdgcn_mfma_f32_16x16x32_bf16(vf, bfrag, oacc[nc], 0, 0, 0);
        }
    }

    short* op = attn + (size_t)(y * WW + x0 + l15) * CC + head * HDIM;
#pragma unroll
    for (int nc = 0; nc < 2; ++nc) {
        short4v o;
#pragma unroll
        for (int r = 0; r < 4; ++r) o[r] = f2bf(oacc[nc][r]);
        *(short4v*)(op + nc * 16 + l4 * 4) = o;
    }
}

// ---------------------------------------------------------------------------
extern "C" void kernel_launch(void* const* d_in, const int* in_sizes, int n_in,
                              void* d_out, int out_size, void* d_ws, size_t ws_size,
                              hipStream_t stream)
{
    const float* x      = (const float*)d_in[0];
    const float* w_qkv  = (const float*)d_in[1];
    const float* b_qkv  = (const float*)d_in[2];
    const float* w_proj = (const float*)d_in[3];
    const float* b_proj = (const float*)d_in[4];
    float* out = (float*)d_out;

    char* ws = (char*)d_ws;
    short* qkv_bf  = (short*)ws;                    // 8192x768 bf16 = 12 MB
    short* attn_bf = (short*)(ws + 12582912);       // 8192x256 bf16 =  4 MB
    short* x_bf    = (short*)(ws + 16777216);       // 8192x256 bf16 =  4 MB
    short* wqkv_t  = (short*)(ws + 20971520);       // 768x256 bf16
    short* wproj_t = (short*)(ws + 21364736);       // 256x256 bf16

    prep<<<dim3(1280), dim3(256), 0, stream>>>(x, w_qkv, w_proj,
                                               x_bf, wqkv_t, wproj_t);

    // QKV: 64x128 tiles, grid (128,6) = 768 blocks = 3.0/CU exact
    gemm_bf<64, 128, false><<<dim3(NPIX / 64, QKV_N / 128), dim3(256), 0, stream>>>(
        x_bf, wqkv_t, b_qkv, qkv_bf, NPIX, QKV_N, CC);

    // attention: 16x8-px blocks, 8 waves, grid (8,8,8) = 512 blocks
    na_mfma<<<dim3(WW / 16, HH / 8, NHEAD), dim3(512), 0, stream>>>(qkv_bf, attn_bf);

    gemm_bf<64, 128, true><<<dim3(NPIX / 64, CC / 128), dim3(256), 0, stream>>>(
        attn_bf, wproj_t, b_proj, out, NPIX, CC, CC);
}